// Round 7
// baseline (11.629 us; speedup 1.0000x reference)
//
#include <hip/hip_runtime.h>
#include <math.h>

#define NN 4096
#define BLK 256
#define EPT 16

__device__ __forceinline__ void cmul(float& ar, float& ai, float br, float bi) {
    float nr = ar * br - ai * bi;
    float ni = ar * bi + ai * br;
    ar = nr; ai = ni;
}

// new_u = u + i*w ; new_w = w + i*u   (1/sqrt2 folded into theta/phi tables)
__device__ __forceinline__ void bfly_pair(float* vr, float* vi, int a, int b) {
    float ur = vr[a], ui = vi[a], wr = vr[b], wi = vi[b];
    vr[a] = ur - wi; vi[a] = ui + wr;
    vr[b] = wr - ui; vi[b] = wi + ur;
}

// butterflies on the 4 register-resident bits (all indices compile-time)
__device__ __forceinline__ void bfly4(float* vr, float* vi) {
    #pragma unroll
    for (int m = 0; m < 4; ++m) {
        #pragma unroll
        for (int a = 0; a < 16; ++a) {
            if (!(a & (1 << m))) bfly_pair(vr, vi, a, a | (1 << m));
        }
    }
}

// element index held by (t, r) at residency P (register bits P..P+3)
template<int P>
__device__ __forceinline__ int jidx(int t, int r) {
    return ((t >> P) << (P + 4)) | (r << P) | (t & ((1 << P) - 1));
}

// XOR swizzle: conflict-free (exact b64 floor) for all three layouts;
// preserves j[11:10] so wave-slice ownership is layout-invariant.
__device__ __forceinline__ int swz(int j) { return j ^ ((j >> 4) & 15); }

template<int P>
__device__ __forceinline__ void wrt(float2* buf, const float* vr, const float* vi, int t) {
    #pragma unroll
    for (int r = 0; r < EPT; ++r) {
        int j = jidx<P>(t, r);
        buf[swz(j)] = make_float2(vr[r], vi[r]);
    }
}

template<int P>
__device__ __forceinline__ void rd(const float2* buf, float* vr, float* vi, int t) {
    #pragma unroll
    for (int r = 0; r < EPT; ++r) {
        int j = jidx<P>(t, r);
        float2 v = buf[swz(j)];
        vr[r] = v.x; vi[r] = v.y;
    }
}

__global__ __launch_bounds__(BLK) void qubit_layer_kernel(
    const float* __restrict__ x,
    const float* __restrict__ alphas, const float* __restrict__ betas,
    const float* __restrict__ thetas, const float* __restrict__ phis,
    float* __restrict__ out)
{
    __shared__ float2 S[NN];        // 32 KB exchange buffer (xor-swizzled)
    __shared__ float2 tbl[6][64];   // 0=in_lo 1=in_hi 2=th_lo(/64) 3=th_hi 4=ph_lo(/64) 5=ph_hi

    const int t = threadIdx.x;
    const int b = blockIdx.x;

    // ---- issue global loads early (P=0 layout: j = t*16 + r) ----
    const float* xr = x + (size_t)b * 2 * NN;
    const float* xi = xr + NN;
    float4 La0 = ((const float4*)(xr + t * EPT))[0];
    float4 La1 = ((const float4*)(xr + t * EPT))[1];
    float4 La2 = ((const float4*)(xr + t * EPT))[2];
    float4 La3 = ((const float4*)(xr + t * EPT))[3];
    float4 Lb0 = ((const float4*)(xi + t * EPT))[0];
    float4 Lb1 = ((const float4*)(xi + t * EPT))[1];
    float4 Lb2 = ((const float4*)(xi + t * EPT))[2];
    float4 Lb3 = ((const float4*)(xi + t * EPT))[3];

    // ---- build phase tables (sincos overlaps the loads) ----
    #pragma unroll
    for (int e = t; e < 384; e += BLK) {
        int part = e >> 6, idx = e & 63, set = part >> 1, half = part & 1;
        float a = 0.f;
        #pragma unroll
        for (int m = 0; m < 6; ++m) {
            int q = half ? m : (6 + m);
            int bit = (idx >> (5 - m)) & 1;
            float av, bv;
            if (set == 0)      { av = alphas[q]; bv = betas[q]; }
            else if (set == 1) { av = thetas[q]; bv = 0.f; }
            else               { av = phis[q];   bv = 0.f; }
            a += bit ? bv : av;
        }
        float s, c;
        __sincosf(a, &s, &c);
        float sc = (set >= 1 && half == 0) ? (1.0f / 64.0f) : 1.0f;
        tbl[part][idx] = make_float2(c * sc, s * sc);
    }
    __syncthreads();   // tables ready

    float vr[EPT], vi[EPT];
    vr[0]=La0.x; vr[1]=La0.y; vr[2]=La0.z; vr[3]=La0.w;
    vr[4]=La1.x; vr[5]=La1.y; vr[6]=La1.z; vr[7]=La1.w;
    vr[8]=La2.x; vr[9]=La2.y; vr[10]=La2.z; vr[11]=La2.w;
    vr[12]=La3.x; vr[13]=La3.y; vr[14]=La3.z; vr[15]=La3.w;
    vi[0]=Lb0.x; vi[1]=Lb0.y; vi[2]=Lb0.z; vi[3]=Lb0.w;
    vi[4]=Lb1.x; vi[5]=Lb1.y; vi[6]=Lb1.z; vi[7]=Lb1.w;
    vi[8]=Lb2.x; vi[9]=Lb2.y; vi[10]=Lb2.z; vi[11]=Lb2.w;
    vi[12]=Lb3.x; vi[13]=Lb3.y; vi[14]=Lb3.z; vi[15]=Lb3.w;

    // ---- D_in at P=0: l = (t&3)<<4 | r  (b128 table reads), h = t>>2 ----
    {
        float2 eh = tbl[1][t >> 2];
        const float4* elv = (const float4*)&tbl[0][(t & 3) << 4];
        #pragma unroll
        for (int k = 0; k < 8; ++k) {
            float4 e2 = elv[k];
            float er0 = e2.x, ei0 = e2.y, er1 = e2.z, ei1 = e2.w;
            cmul(er0, ei0, eh.x, eh.y);
            cmul(er1, ei1, eh.x, eh.y);
            cmul(vr[2*k],   vi[2*k],   er0, ei0);
            cmul(vr[2*k+1], vi[2*k+1], er1, ei1);
        }
    }

    // ---- BS1 ----
    bfly4(vr, vi);                              // bits 0-3
    wrt<0>(S, vr, vi, t);                       // private (wave slice invariant 0<->4)
    asm volatile("" ::: "memory");
    rd<4>(S, vr, vi, t);
    bfly4(vr, vi);                              // bits 4-7
    wrt<4>(S, vr, vi, t);                       // cross
    __syncthreads();
    rd<8>(S, vr, vi, t);
    bfly4(vr, vi);                              // bits 8-11

    // ---- D_theta at P=8 (j = r*256 + t): l = t&63, h = (r<<2)|(t>>6) ----
    {
        float2 el = tbl[2][t & 63];
        #pragma unroll
        for (int r = 0; r < EPT; ++r) {
            float2 eh = tbl[3][(r << 2) | (t >> 6)];
            float er = el.x, ei = el.y;
            cmul(er, ei, eh.x, eh.y);
            cmul(vr[r], vi[r], er, ei);
        }
    }

    // ---- BS2 (down-ladder) ----
    bfly4(vr, vi);                              // bits 8-11
    __syncthreads();                            // all rd<8> above complete
    wrt<8>(S, vr, vi, t);                       // cross
    __syncthreads();
    rd<4>(S, vr, vi, t);
    bfly4(vr, vi);                              // bits 4-7
    wrt<4>(S, vr, vi, t);                       // private (4<->0)
    asm volatile("" ::: "memory");
    rd<0>(S, vr, vi, t);
    bfly4(vr, vi);                              // bits 0-3

    // ---- D_phi at P=0 + stores ----
    {
        float2 eh = tbl[5][t >> 2];
        const float4* elv = (const float4*)&tbl[4][(t & 3) << 4];
        #pragma unroll
        for (int k = 0; k < 8; ++k) {
            float4 e2 = elv[k];
            float er0 = e2.x, ei0 = e2.y, er1 = e2.z, ei1 = e2.w;
            cmul(er0, ei0, eh.x, eh.y);
            cmul(er1, ei1, eh.x, eh.y);
            cmul(vr[2*k],   vi[2*k],   er0, ei0);
            cmul(vr[2*k+1], vi[2*k+1], er1, ei1);
        }
    }
    float* outr = out + (size_t)b * 2 * NN;
    float* outi = outr + NN;
    ((float4*)(outr + t * EPT))[0] = make_float4(vr[0], vr[1], vr[2], vr[3]);
    ((float4*)(outr + t * EPT))[1] = make_float4(vr[4], vr[5], vr[6], vr[7]);
    ((float4*)(outr + t * EPT))[2] = make_float4(vr[8], vr[9], vr[10], vr[11]);
    ((float4*)(outr + t * EPT))[3] = make_float4(vr[12], vr[13], vr[14], vr[15]);
    ((float4*)(outi + t * EPT))[0] = make_float4(vi[0], vi[1], vi[2], vi[3]);
    ((float4*)(outi + t * EPT))[1] = make_float4(vi[4], vi[5], vi[6], vi[7]);
    ((float4*)(outi + t * EPT))[2] = make_float4(vi[8], vi[9], vi[10], vi[11]);
    ((float4*)(outi + t * EPT))[3] = make_float4(vi[12], vi[13], vi[14], vi[15]);
}

extern "C" void kernel_launch(void* const* d_in, const int* in_sizes, int n_in,
                              void* d_out, int out_size, void* d_ws, size_t ws_size,
                              hipStream_t stream) {
    const float* x      = (const float*)d_in[0];
    const float* alphas = (const float*)d_in[1];
    const float* betas  = (const float*)d_in[2];
    const float* thetas = (const float*)d_in[3];
    const float* phis   = (const float*)d_in[4];
    float* out = (float*)d_out;

    const int batch = in_sizes[0] / (2 * NN);   // 64
    qubit_layer_kernel<<<batch, BLK, 0, stream>>>(x, alphas, betas, thetas, phis, out);
}